// Round 1
// baseline (1837.014 us; speedup 1.0000x reference)
//
#include <hip/hip_runtime.h>

#define Hd 128

__global__ __launch_bounds__(256) void zero_kernel(int* __restrict__ p, int n) {
    int i = blockIdx.x * 256 + threadIdx.x;
    if (i < n) p[i] = 0;
}

__global__ __launch_bounds__(256) void count_kernel(const int* __restrict__ dst,
                                                    const int* __restrict__ et,
                                                    int* __restrict__ cnt, int E, int N) {
    int e = blockIdx.x * 256 + threadIdx.x;
    if (e < E) atomicAdd(&cnt[et[e] * N + dst[e]], 1);
}

__global__ __launch_bounds__(256) void inv_kernel(const int* __restrict__ cnt,
                                                  float* __restrict__ inv, int n) {
    int i = blockIdx.x * 256 + threadIdx.x;
    if (i < n) inv[i] = 1.0f / (float)max(cnt[i], 1);
}

// C[M,128] = A[M,128] @ B[128,128] (+ bias). 64-row tile/block, B fully in LDS.
__global__ __launch_bounds__(256, 2) void gemm128(const float* __restrict__ A,
                                                  const float* __restrict__ B,
                                                  const float* __restrict__ bias,
                                                  float* __restrict__ C, int M) {
    __shared__ float Bs[128 * 128];   // 64 KB
    __shared__ float As[64 * 36];     // padded stride 36: breaks bank aliasing, keeps 16B align
    const int tid = threadIdx.x;
    const int tx = tid & 15;          // col group: 8 cols each
    const int ty = tid >> 4;          // row group: 4 rows each
    const int rowBase = blockIdx.x * 64;

    const float4* B4 = (const float4*)B;
    float4* Bs4 = (float4*)Bs;
#pragma unroll
    for (int i = 0; i < 16; ++i) Bs4[tid + i * 256] = B4[tid + i * 256];

    float acc[4][8];
#pragma unroll
    for (int i = 0; i < 4; ++i)
#pragma unroll
        for (int j = 0; j < 8; ++j) acc[i][j] = 0.f;

    for (int c = 0; c < 4; ++c) {     // K chunks of 32
        __syncthreads();
#pragma unroll
        for (int j = 0; j < 2; ++j) {  // stage A chunk: 512 float4 / 256 threads
            int f = tid * 2 + j;
            int r = f >> 3, k4 = f & 7;
            int row = rowBase + r;
            if (row >= M) row = 0;     // clamp; stores guarded below
            *(float4*)&As[r * 36 + k4 * 4] =
                *(const float4*)&A[(size_t)row * Hd + c * 32 + k4 * 4];
        }
        __syncthreads();
#pragma unroll
        for (int kk = 0; kk < 32; ++kk) {
            const int kg = c * 32 + kk;
            float aa[4];
#pragma unroll
            for (int i = 0; i < 4; ++i) aa[i] = As[(ty * 4 + i) * 36 + kk];
            float4 b0 = Bs4[kg * 32 + tx * 2];
            float4 b1 = Bs4[kg * 32 + tx * 2 + 1];
            float bb[8] = {b0.x, b0.y, b0.z, b0.w, b1.x, b1.y, b1.z, b1.w};
#pragma unroll
            for (int i = 0; i < 4; ++i)
#pragma unroll
                for (int j = 0; j < 8; ++j) acc[i][j] = fmaf(aa[i], bb[j], acc[i][j]);
        }
    }

    float bb0[8] = {0, 0, 0, 0, 0, 0, 0, 0};
    if (bias) {
#pragma unroll
        for (int j = 0; j < 8; ++j) bb0[j] = bias[tx * 8 + j];
    }
#pragma unroll
    for (int i = 0; i < 4; ++i) {
        int row = rowBase + ty * 4 + i;
        if (row < M) {
            float4 o0 = make_float4(acc[i][0] + bb0[0], acc[i][1] + bb0[1],
                                    acc[i][2] + bb0[2], acc[i][3] + bb0[3]);
            float4 o1 = make_float4(acc[i][4] + bb0[4], acc[i][5] + bb0[5],
                                    acc[i][6] + bb0[6], acc[i][7] + bb0[7]);
            *(float4*)&C[(size_t)row * Hd + tx * 8] = o0;
            *(float4*)&C[(size_t)row * Hd + tx * 8 + 4] = o1;
        }
    }
}

// One wave per edge iteration; message scaled by inv count then atomically accumulated.
__global__ __launch_bounds__(256) void scatter_kernel(const float* __restrict__ xr,
                                                      const int* __restrict__ src,
                                                      const int* __restrict__ dst,
                                                      const int* __restrict__ et,
                                                      const float* __restrict__ invr,
                                                      float* __restrict__ acc, int E, int rel) {
    int gw = (blockIdx.x * 256 + threadIdx.x) >> 6;
    int lane = threadIdx.x & 63;
    int nw = (gridDim.x * 256) >> 6;
    for (int e = gw; e < E; e += nw) {
        if (et[e] != rel) continue;
        int s = src[e], d = dst[e];
        float w = invr[d];
        float v0 = xr[(size_t)s * Hd + lane] * w;
        float v1 = xr[(size_t)s * Hd + 64 + lane] * w;
        atomicAdd(&acc[(size_t)d * Hd + lane], v0);
        atomicAdd(&acc[(size_t)d * Hd + 64 + lane], v1);
    }
}

__global__ __launch_bounds__(256) void relu_kernel(const float* __restrict__ in,
                                                   float* __restrict__ out, int n4) {
    int i = blockIdx.x * 256 + threadIdx.x;
    if (i < n4) {
        float4 v = ((const float4*)in)[i];
        v.x = fmaxf(v.x, 0.f); v.y = fmaxf(v.y, 0.f);
        v.z = fmaxf(v.z, 0.f); v.w = fmaxf(v.w, 0.f);
        ((float4*)out)[i] = v;
    }
}

// out[i] = relu(acc[i]) . Wc + bc   (relu of layer-2 fused here)
__global__ __launch_bounds__(256) void classify_kernel(const float* __restrict__ acc,
                                                       const float* __restrict__ Wc,
                                                       const float* __restrict__ bc,
                                                       float* __restrict__ out, int N) {
    int wave = (blockIdx.x * 256 + threadIdx.x) >> 6;
    int lane = threadIdx.x & 63;
    if (wave >= N) return;
    float s = fmaxf(acc[(size_t)wave * Hd + lane], 0.f) * Wc[lane]
            + fmaxf(acc[(size_t)wave * Hd + 64 + lane], 0.f) * Wc[64 + lane];
#pragma unroll
    for (int off = 32; off > 0; off >>= 1) s += __shfl_down(s, off);
    if (lane == 0) out[wave] = s + bc[0];
}

extern "C" void kernel_launch(void* const* d_in, const int* in_sizes, int n_in,
                              void* d_out, int out_size, void* d_ws, size_t ws_size,
                              hipStream_t stream) {
    const float* x     = (const float*)d_in[0];
    const int*   ei    = (const int*)d_in[1];
    const int*   et    = (const int*)d_in[2];
    const float* W1    = (const float*)d_in[3];
    const float* root1 = (const float*)d_in[4];
    const float* b1    = (const float*)d_in[5];
    const float* W2    = (const float*)d_in[6];
    const float* root2 = (const float*)d_in[7];
    const float* b2    = (const float*)d_in[8];
    const float* Wc    = (const float*)d_in[9];
    const float* bc    = (const float*)d_in[10];
    float* out = (float*)d_out;

    const int N = in_sizes[0] / Hd;
    const int E = in_sizes[2];
    const int R = in_sizes[3] / (Hd * Hd);
    const int* src  = ei;
    const int* dstp = ei + E;

    // workspace layout (floats): inv[R*N] | cnt[R*N] | acc[N*H] | h[N*H] | xr[N*H]
    const size_t RN = (size_t)R * N;
    const size_t NH = (size_t)N * Hd;
    const size_t need = (2 * RN + 3 * NH) * sizeof(float);
    if (ws_size < need) return;  // insufficient scratch — will show as wrong answer

    float* f    = (float*)d_ws;
    float* inv  = f;
    int*   cnt  = (int*)(f + RN);
    float* accb = f + 2 * RN;
    float* hbuf = accb + NH;
    float* xr   = hbuf + NH;

    const int RNi = (int)RN;
    zero_kernel<<<(RNi + 255) / 256, 256, 0, stream>>>(cnt, RNi);
    count_kernel<<<(E + 255) / 256, 256, 0, stream>>>(dstp, et, cnt, E, N);
    inv_kernel<<<(RNi + 255) / 256, 256, 0, stream>>>(cnt, inv, RNi);

    const int gblocks = (N + 63) / 64;

    // layer 1
    gemm128<<<gblocks, 256, 0, stream>>>(x, root1, b1, accb, N);
    for (int r = 0; r < R; ++r) {
        gemm128<<<gblocks, 256, 0, stream>>>(x, W1 + (size_t)r * Hd * Hd, nullptr, xr, N);
        scatter_kernel<<<1024, 256, 0, stream>>>(xr, src, dstp, et, inv + (size_t)r * N,
                                                 accb, E, r);
    }
    relu_kernel<<<((N * Hd / 4) + 255) / 256, 256, 0, stream>>>(accb, hbuf, N * Hd / 4);

    // layer 2
    gemm128<<<gblocks, 256, 0, stream>>>(hbuf, root2, b2, accb, N);
    for (int r = 0; r < R; ++r) {
        gemm128<<<gblocks, 256, 0, stream>>>(hbuf, W2 + (size_t)r * Hd * Hd, nullptr, xr, N);
        scatter_kernel<<<1024, 256, 0, stream>>>(xr, src, dstp, et, inv + (size_t)r * N,
                                                 accb, E, r);
    }

    classify_kernel<<<(N + 3) / 4, 256, 0, stream>>>(accb, Wc, bc, out, N);
}

// Round 2
// 1087.889 us; speedup vs baseline: 1.6886x; 1.6886x over previous
//
#include <hip/hip_runtime.h>

#define Hd 128
#define LDA 136   // LDS leading dim (bf16 elems): 272B rows -> 4-bank rotation, 2-way max

typedef __attribute__((ext_vector_type(8))) short short8;   // 8 bf16 = 4 VGPRs
typedef __attribute__((ext_vector_type(4))) float f32x4;

__device__ __forceinline__ unsigned short f2bf(float f) {
    union { float f; unsigned u; } v; v.f = f;
    unsigned r = v.u + 0x7FFFu + ((v.u >> 16) & 1u);   // RNE
    return (unsigned short)(r >> 16);
}

// ---------- graph prep ----------
__global__ __launch_bounds__(256) void zero_kernel(int* __restrict__ p, int n) {
    int i = blockIdx.x * 256 + threadIdx.x;
    if (i < n) p[i] = 0;
}

__global__ __launch_bounds__(256) void count_kernel(const int* __restrict__ dst,
                                                    const int* __restrict__ et,
                                                    int* __restrict__ cnt, int E, int N) {
    int e = blockIdx.x * 256 + threadIdx.x;
    if (e < E) atomicAdd(&cnt[et[e] * N + dst[e]], 1);
}

__global__ __launch_bounds__(256) void inv_kernel(const int* __restrict__ cnt,
                                                  float* __restrict__ inv, int n) {
    int i = blockIdx.x * 256 + threadIdx.x;
    if (i < n) inv[i] = 1.0f / (float)max(cnt[i], 1);
}

// ---------- dtype prep ----------
// fp32 -> bf16, optional relu. n4 = elements/4.
__global__ __launch_bounds__(256) void cvt_bf16_kernel(const float* __restrict__ in,
                                                       unsigned short* __restrict__ out,
                                                       int n4, int doRelu) {
    int i = blockIdx.x * 256 + threadIdx.x;
    if (i >= n4) return;
    float4 v = ((const float4*)in)[i];
    if (doRelu) {
        v.x = fmaxf(v.x, 0.f); v.y = fmaxf(v.y, 0.f);
        v.z = fmaxf(v.z, 0.f); v.w = fmaxf(v.w, 0.f);
    }
    ushort4 o;
    o.x = f2bf(v.x); o.y = f2bf(v.y); o.z = f2bf(v.z); o.w = f2bf(v.w);
    ((ushort4*)out)[i] = o;
}

// One 128x128 matrix per block: Bt[n*128+k] = bf16(W[k*128+n])
__global__ __launch_bounds__(256) void prep_w_kernel(const float* __restrict__ W,
                                                     unsigned short* __restrict__ Bt) {
    __shared__ float S[128 * 129];
    const float* Ws = W + (size_t)blockIdx.x * 16384;
    unsigned short* Bd = Bt + (size_t)blockIdx.x * 16384;
    const int tid = threadIdx.x;
#pragma unroll 8
    for (int i = 0; i < 64; ++i) {
        int idx = i * 256 + tid;
        S[(idx >> 7) * 129 + (idx & 127)] = Ws[idx];
    }
    __syncthreads();
#pragma unroll 8
    for (int i = 0; i < 64; ++i) {
        int idx = i * 256 + tid;
        int n = idx >> 7, k = idx & 127;
        Bd[idx] = f2bf(S[k * 129 + n]);
    }
}

// ---------- MFMA GEMM: C[M,128] = A[M,128] @ B, B given transposed (n-major) ----------
// mode 0: Cf[row,col] = acc + bias[col]   (fp32 out)
// mode 1: Cb + blockIdx.y*nh : bf16 out; Bt selected by blockIdx.y
__global__ __launch_bounds__(256, 2) void gemm_mfma(const unsigned short* __restrict__ A,
                                                    const unsigned short* __restrict__ Bt0,
                                                    const float* __restrict__ bias,
                                                    float* __restrict__ Cf,
                                                    unsigned short* __restrict__ Cb,
                                                    int M, int mode, int nh) {
    __shared__ __align__(16) unsigned short As[128 * LDA];
    __shared__ __align__(16) unsigned short Bs[128 * LDA];
    const int tid = threadIdx.x;
    const int rowBase = blockIdx.x * 128;
    const unsigned short* Bt = Bt0 + (size_t)blockIdx.y * 16384;

    // stage A tile (clamped rows) + full Bt, 16B vector loads
#pragma unroll
    for (int i = 0; i < 8; ++i) {
        int idx = i * 256 + tid;            // 0..2047
        int r = idx >> 4, c16 = idx & 15;   // r in [0,128), c16 in [0,16)
        int grow = rowBase + r; if (grow >= M) grow = M - 1;
        *(float4*)&As[r * LDA + c16 * 8] = *(const float4*)&A[(size_t)grow * Hd + c16 * 8];
        *(float4*)&Bs[r * LDA + c16 * 8] = *(const float4*)&Bt[idx * 8];
    }
    __syncthreads();

    const int wave = tid >> 6;
    const int lane = tid & 63;
    const int lm = lane & 15;
    const int lk = (lane >> 4) * 8;

    f32x4 acc[2][8];
#pragma unroll
    for (int mt = 0; mt < 2; ++mt)
#pragma unroll
        for (int nt = 0; nt < 8; ++nt) acc[mt][nt] = (f32x4){0.f, 0.f, 0.f, 0.f};

#pragma unroll
    for (int ks = 0; ks < 4; ++ks) {
        const int k0 = ks * 32 + lk;
        short8 af0 = *(const short8*)&As[(wave * 32 + lm) * LDA + k0];
        short8 af1 = *(const short8*)&As[(wave * 32 + 16 + lm) * LDA + k0];
#pragma unroll
        for (int nt = 0; nt < 8; ++nt) {
            short8 bf = *(const short8*)&Bs[(nt * 16 + lm) * LDA + k0];
            acc[0][nt] = __builtin_amdgcn_mfma_f32_16x16x32_bf16(af0, bf, acc[0][nt], 0, 0, 0);
            acc[1][nt] = __builtin_amdgcn_mfma_f32_16x16x32_bf16(af1, bf, acc[1][nt], 0, 0, 0);
        }
    }

    // epilogue: C/D layout col=lane&15, row=(lane>>4)*4+reg  [m89-verified]
    const int rquad = (lane >> 4) * 4;
    unsigned short* CbY = Cb ? Cb + (size_t)blockIdx.y * nh : (unsigned short*)0;
#pragma unroll
    for (int mt = 0; mt < 2; ++mt)
#pragma unroll
        for (int reg = 0; reg < 4; ++reg) {
            int row = rowBase + wave * 32 + mt * 16 + rquad + reg;
            if (row >= M) continue;
#pragma unroll
            for (int nt = 0; nt < 8; ++nt) {
                int col = nt * 16 + lm;
                float v = acc[mt][nt][reg];
                if (mode == 0) Cf[(size_t)row * Hd + col] = v + bias[col];
                else           CbY[(size_t)row * Hd + col] = f2bf(v);
            }
        }
}

// ---------- fused scatter: all relations in [r0,r1) in one edge pass ----------
__global__ __launch_bounds__(256) void scatter_fused(const unsigned short* __restrict__ xr,
                                                     const int* __restrict__ src,
                                                     const int* __restrict__ dst,
                                                     const int* __restrict__ et,
                                                     const float* __restrict__ inv,
                                                     float* __restrict__ acc,
                                                     int E, int N, int r0, int r1) {
    const int lane = threadIdx.x & 63;
    const int wid = (blockIdx.x * 256 + threadIdx.x) >> 6;
    const int nw = (gridDim.x * 256) >> 6;
    const int NHl = N * Hd;
    const int nBatch = (E + 63) >> 6;
    const uint* xr32 = (const uint*)xr;

    for (int b = wid; b < nBatch; b += nw) {
        int e = (b << 6) + lane;
        int offv = -1, dv = 0; float wv = 0.f;
        if (e < E) {
            int rel = et[e];
            if (rel >= r0 && rel < r1) {
                dv = dst[e];
                wv = inv[rel * N + dv];
                offv = ((rel - r0) * NHl + src[e] * Hd) >> 1;   // uint index (bf16 pairs)
            }
        }
#pragma unroll 4
        for (int i = 0; i < 64; ++i) {
            int off = __shfl(offv, i);
            if (off < 0) continue;
            int d = __shfl(dv, i);
            float w = __shfl(wv, i);
            uint val = xr32[off + lane];                      // 2 bf16: cols 2*lane, 2*lane+1
            float flo = __uint_as_float(val << 16) * w;
            float fhi = __uint_as_float(val & 0xffff0000u) * w;
            float* ap = &acc[(size_t)d * Hd + 2 * lane];
            atomicAdd(ap, flo);
            atomicAdd(ap + 1, fhi);
        }
    }
}

// ---------- classifier: out[i] = relu(acc[i]) . Wc + bc ----------
__global__ __launch_bounds__(256) void classify_kernel(const float* __restrict__ acc,
                                                       const float* __restrict__ Wc,
                                                       const float* __restrict__ bc,
                                                       float* __restrict__ out, int N) {
    int wave = (blockIdx.x * 256 + threadIdx.x) >> 6;
    int lane = threadIdx.x & 63;
    if (wave >= N) return;
    float s = fmaxf(acc[(size_t)wave * Hd + lane], 0.f) * Wc[lane]
            + fmaxf(acc[(size_t)wave * Hd + 64 + lane], 0.f) * Wc[64 + lane];
#pragma unroll
    for (int off = 32; off > 0; off >>= 1) s += __shfl_down(s, off);
    if (lane == 0) out[wave] = s + bc[0];
}

extern "C" void kernel_launch(void* const* d_in, const int* in_sizes, int n_in,
                              void* d_out, int out_size, void* d_ws, size_t ws_size,
                              hipStream_t stream) {
    const float* x     = (const float*)d_in[0];
    const int*   ei    = (const int*)d_in[1];
    const int*   et    = (const int*)d_in[2];
    const float* W1    = (const float*)d_in[3];
    const float* root1 = (const float*)d_in[4];
    const float* b1    = (const float*)d_in[5];
    const float* W2    = (const float*)d_in[6];
    const float* root2 = (const float*)d_in[7];
    const float* b2    = (const float*)d_in[8];
    const float* Wc    = (const float*)d_in[9];
    const float* bc    = (const float*)d_in[10];
    float* out = (float*)d_out;

    const int N = in_sizes[0] / Hd;
    const int E = in_sizes[2];
    const int R = in_sizes[3] / (Hd * Hd);
    const int* src  = ei;
    const int* dstp = ei + E;

    const size_t NH = (size_t)N * Hd;
    const size_t RN = (size_t)R * N;

    // workspace carve-up (256B aligned)
    size_t off = 0;
    auto carve = [&](size_t bytes) -> char* {
        char* p = (char*)d_ws + off;
        off += (bytes + 255) & ~(size_t)255;
        return p;
    };
    float*          accb = (float*)carve(NH * 4);
    unsigned short* xbf  = (unsigned short*)carve(NH * 2);
    unsigned short* Bt   = (unsigned short*)carve((size_t)2 * 9 * 16384 * 2);
    int*            cnt  = (int*)carve(RN * 4);
    float*          inv  = (float*)carve(RN * 4);
    int RC = R;                                   // relations per chunk, shrink to fit
    while (RC > 1 && off + (size_t)RC * NH * 2 > ws_size) RC >>= 1;
    if (off + (size_t)RC * NH * 2 > ws_size) return;
    unsigned short* xr = (unsigned short*)((char*)d_ws + off);

    const int RNi = (int)RN;
    zero_kernel<<<(RNi + 255) / 256, 256, 0, stream>>>(cnt, RNi);
    count_kernel<<<(E + 255) / 256, 256, 0, stream>>>(dstp, et, cnt, E, N);
    inv_kernel<<<(RNi + 255) / 256, 256, 0, stream>>>(cnt, inv, RNi);

    const int n4 = (int)(NH / 4);
    cvt_bf16_kernel<<<(n4 + 255) / 256, 256, 0, stream>>>(x, xbf, n4, 0);

    // weights -> bf16 transposed: layout [L1 root | L1 W0..W7 | L2 root | L2 W0..W7]
    prep_w_kernel<<<1, 256, 0, stream>>>(root1, Bt);
    prep_w_kernel<<<R, 256, 0, stream>>>(W1,    Bt + (size_t)1 * 16384);
    prep_w_kernel<<<1, 256, 0, stream>>>(root2, Bt + (size_t)9 * 16384);
    prep_w_kernel<<<R, 256, 0, stream>>>(W2,    Bt + (size_t)10 * 16384);

    const int Mtiles = (N + 127) / 128;

    for (int layer = 0; layer < 2; ++layer) {
        const unsigned short* BtL = Bt + (size_t)layer * 9 * 16384;
        const float* bias = layer ? b2 : b1;
        // root: acc = A @ root + bias (fp32)
        gemm_mfma<<<dim3(Mtiles, 1), 256, 0, stream>>>(xbf, BtL, bias, accb, nullptr,
                                                       N, 0, (int)NH);
        for (int r0 = 0; r0 < R; r0 += RC) {
            int rc = min(RC, R - r0);
            gemm_mfma<<<dim3(Mtiles, rc), 256, 0, stream>>>(
                xbf, BtL + (size_t)(1 + r0) * 16384, nullptr, nullptr, xr, N, 1, (int)NH);
            scatter_fused<<<1024, 256, 0, stream>>>(xr, src, dstp, et, inv, accb,
                                                    E, N, r0, r0 + rc);
        }
        if (layer == 0)
            cvt_bf16_kernel<<<(n4 + 255) / 256, 256, 0, stream>>>(accb, xbf, n4, 1);
    }

    classify_kernel<<<(N + 3) / 4, 256, 0, stream>>>(accb, Wc, bc, out, N);
}

// Round 3
// 502.283 us; speedup vs baseline: 3.6573x; 2.1659x over previous
//
#include <hip/hip_runtime.h>

#define Hd 128
#define LDA 136   // LDS leading dim (bf16 elems)

typedef __attribute__((ext_vector_type(8))) short short8;   // 8 bf16 = 4 VGPRs
typedef __attribute__((ext_vector_type(4))) float f32x4;

__device__ __forceinline__ unsigned short f2bf(float f) {
    union { float f; unsigned u; } v; v.f = f;
    unsigned r = v.u + 0x7FFFu + ((v.u >> 16) & 1u);   // RNE
    return (unsigned short)(r >> 16);
}

// ---------- graph prep ----------
__global__ __launch_bounds__(256) void zero_kernel(int* __restrict__ p, int n) {
    int i = blockIdx.x * 256 + threadIdx.x;
    if (i < n) p[i] = 0;
}

// per-(rel,dst) counts + per-dst degree
__global__ __launch_bounds__(256) void count_kernel(const int* __restrict__ dst,
                                                    const int* __restrict__ et,
                                                    int* __restrict__ cnt,
                                                    int* __restrict__ cntd, int E, int N) {
    int e = blockIdx.x * 256 + threadIdx.x;
    if (e < E) {
        int d = dst[e];
        atomicAdd(&cnt[et[e] * N + d], 1);
        atomicAdd(&cntd[d], 1);
    }
}

__global__ __launch_bounds__(256) void inv_kernel(const int* __restrict__ cnt,
                                                  float* __restrict__ inv, int n) {
    int i = blockIdx.x * 256 + threadIdx.x;
    if (i < n) inv[i] = 1.0f / (float)max(cnt[i], 1);
}

// single-block exclusive scan of cntd[N] -> row_ptr, cursor
__global__ __launch_bounds__(1024) void scan_kernel(const int* __restrict__ cntd,
                                                    int* __restrict__ row_ptr,
                                                    int* __restrict__ cursor, int N, int E) {
    __shared__ int wsum[16];
    const int tid = threadIdx.x;
    const int lane = tid & 63, wid = tid >> 6;
    const int chunk = (N + 1023) >> 10;
    const int beg = tid * chunk;
    const int end = min(beg + chunk, N);
    int s = 0;
    for (int i = beg; i < end; ++i) s += cntd[i];
    int v = s;                                  // inclusive wave scan
#pragma unroll
    for (int off = 1; off < 64; off <<= 1) {
        int t = __shfl_up(v, off);
        if (lane >= off) v += t;
    }
    if (lane == 63) wsum[wid] = v;
    __syncthreads();
    if (wid == 0) {
        int w = (lane < 16) ? wsum[lane] : 0;
        int vw = w;
#pragma unroll
        for (int off = 1; off < 16; off <<= 1) {
            int t = __shfl_up(vw, off);
            if (lane >= off) vw += t;
        }
        if (lane < 16) wsum[lane] = vw - w;     // exclusive wave prefix
    }
    __syncthreads();
    int run = wsum[wid] + (v - s);              // exclusive prefix for this thread
    for (int i = beg; i < end; ++i) {
        row_ptr[i] = run; cursor[i] = run; run += cntd[i];
    }
    if (tid == 0) row_ptr[N] = E;
}

// counting-sort placement: epk sorted by dst, payload = (src<<3)|rel
__global__ __launch_bounds__(256) void place_kernel(const int* __restrict__ src,
                                                    const int* __restrict__ dst,
                                                    const int* __restrict__ et,
                                                    int* __restrict__ cursor,
                                                    unsigned int* __restrict__ epk, int E) {
    int e = blockIdx.x * 256 + threadIdx.x;
    if (e < E) {
        int pos = atomicAdd(&cursor[dst[e]], 1);
        epk[pos] = ((unsigned int)src[e] << 3) | (unsigned int)et[e];
    }
}

// ---------- dtype prep ----------
__global__ __launch_bounds__(256) void cvt_bf16_kernel(const float* __restrict__ in,
                                                       unsigned short* __restrict__ out,
                                                       int n4, int doRelu) {
    int i = blockIdx.x * 256 + threadIdx.x;
    if (i >= n4) return;
    float4 v = ((const float4*)in)[i];
    if (doRelu) {
        v.x = fmaxf(v.x, 0.f); v.y = fmaxf(v.y, 0.f);
        v.z = fmaxf(v.z, 0.f); v.w = fmaxf(v.w, 0.f);
    }
    ushort4 o;
    o.x = f2bf(v.x); o.y = f2bf(v.y); o.z = f2bf(v.z); o.w = f2bf(v.w);
    ((ushort4*)out)[i] = o;
}

// One 128x128 matrix per block: Bt[n*128+k] = bf16(W[k*128+n])
__global__ __launch_bounds__(256) void prep_w_kernel(const float* __restrict__ W,
                                                     unsigned short* __restrict__ Bt) {
    __shared__ float S[128 * 129];
    const float* Ws = W + (size_t)blockIdx.x * 16384;
    unsigned short* Bd = Bt + (size_t)blockIdx.x * 16384;
    const int tid = threadIdx.x;
#pragma unroll 8
    for (int i = 0; i < 64; ++i) {
        int idx = i * 256 + tid;
        S[(idx >> 7) * 129 + (idx & 127)] = Ws[idx];
    }
    __syncthreads();
#pragma unroll 8
    for (int i = 0; i < 64; ++i) {
        int idx = i * 256 + tid;
        int n = idx >> 7, k = idx & 127;
        Bd[idx] = f2bf(S[k * 129 + n]);
    }
}

// ---------- root GEMM: Cf[M,128] = A @ root + bias (fp32 out) ----------
__global__ __launch_bounds__(256, 2) void gemm_root(const unsigned short* __restrict__ A,
                                                    const unsigned short* __restrict__ Bt,
                                                    const float* __restrict__ bias,
                                                    float* __restrict__ Cf, int M) {
    __shared__ __align__(16) unsigned short As[128 * LDA];
    __shared__ __align__(16) unsigned short Bs[128 * LDA];
    const int tid = threadIdx.x;
    const int rowBase = blockIdx.x * 128;
#pragma unroll
    for (int i = 0; i < 8; ++i) {
        int idx = i * 256 + tid;
        int r = idx >> 4, c16 = idx & 15;
        int grow = rowBase + r; if (grow >= M) grow = M - 1;
        *(float4*)&As[r * LDA + c16 * 8] = *(const float4*)&A[(size_t)grow * Hd + c16 * 8];
        *(float4*)&Bs[r * LDA + c16 * 8] = *(const float4*)&Bt[idx * 8];
    }
    __syncthreads();

    const int wave = tid >> 6, lane = tid & 63;
    const int lm = lane & 15, lk = (lane >> 4) * 8;
    f32x4 acc[2][8];
#pragma unroll
    for (int mt = 0; mt < 2; ++mt)
#pragma unroll
        for (int nt = 0; nt < 8; ++nt) acc[mt][nt] = (f32x4){0.f, 0.f, 0.f, 0.f};
#pragma unroll
    for (int ks = 0; ks < 4; ++ks) {
        const int k0 = ks * 32 + lk;
        short8 af0 = *(const short8*)&As[(wave * 32 + lm) * LDA + k0];
        short8 af1 = *(const short8*)&As[(wave * 32 + 16 + lm) * LDA + k0];
#pragma unroll
        for (int nt = 0; nt < 8; ++nt) {
            short8 bf = *(const short8*)&Bs[(nt * 16 + lm) * LDA + k0];
            acc[0][nt] = __builtin_amdgcn_mfma_f32_16x16x32_bf16(af0, bf, acc[0][nt], 0, 0, 0);
            acc[1][nt] = __builtin_amdgcn_mfma_f32_16x16x32_bf16(af1, bf, acc[1][nt], 0, 0, 0);
        }
    }
    const int rquad = (lane >> 4) * 4;
#pragma unroll
    for (int mt = 0; mt < 2; ++mt)
#pragma unroll
        for (int reg = 0; reg < 4; ++reg) {
            int row = rowBase + wave * 32 + mt * 16 + rquad + reg;
            if (row >= M) continue;
#pragma unroll
            for (int nt = 0; nt < 8; ++nt) {
                int col = nt * 16 + lm;
                Cf[(size_t)row * Hd + col] = acc[mt][nt][reg] + bias[col];
            }
        }
}

// ---------- relation GEMMs, A staged once, loop over rc relations ----------
__global__ __launch_bounds__(256, 2) void gemm_rel(const unsigned short* __restrict__ A,
                                                   const unsigned short* __restrict__ Bt,
                                                   unsigned short* __restrict__ Cb,
                                                   int M, int rc, int nh) {
    __shared__ __align__(16) unsigned short As[128 * LDA];
    __shared__ __align__(16) unsigned short Bs[128 * LDA];
    const int tid = threadIdx.x;
    const int rowBase = blockIdx.x * 128;
#pragma unroll
    for (int i = 0; i < 8; ++i) {
        int idx = i * 256 + tid;
        int r = idx >> 4, c16 = idx & 15;
        int grow = rowBase + r; if (grow >= M) grow = M - 1;
        *(float4*)&As[r * LDA + c16 * 8] = *(const float4*)&A[(size_t)grow * Hd + c16 * 8];
    }
    const int wave = tid >> 6, lane = tid & 63;
    const int lm = lane & 15, lk = (lane >> 4) * 8;
    const int rquad = (lane >> 4) * 4;

    for (int rr = 0; rr < rc; ++rr) {
        __syncthreads();   // previous iter's Bs reads done (and As staged, iter 0)
        const unsigned short* Btr = Bt + (size_t)rr * 16384;
#pragma unroll
        for (int i = 0; i < 8; ++i) {
            int idx = i * 256 + tid;
            *(float4*)&Bs[(idx >> 4) * LDA + (idx & 15) * 8] = *(const float4*)&Btr[idx * 8];
        }
        __syncthreads();

        f32x4 acc[2][8];
#pragma unroll
        for (int mt = 0; mt < 2; ++mt)
#pragma unroll
            for (int nt = 0; nt < 8; ++nt) acc[mt][nt] = (f32x4){0.f, 0.f, 0.f, 0.f};
#pragma unroll
        for (int ks = 0; ks < 4; ++ks) {
            const int k0 = ks * 32 + lk;
            short8 af0 = *(const short8*)&As[(wave * 32 + lm) * LDA + k0];
            short8 af1 = *(const short8*)&As[(wave * 32 + 16 + lm) * LDA + k0];
#pragma unroll
            for (int nt = 0; nt < 8; ++nt) {
                short8 bf = *(const short8*)&Bs[(nt * 16 + lm) * LDA + k0];
                acc[0][nt] = __builtin_amdgcn_mfma_f32_16x16x32_bf16(af0, bf, acc[0][nt], 0, 0, 0);
                acc[1][nt] = __builtin_amdgcn_mfma_f32_16x16x32_bf16(af1, bf, acc[1][nt], 0, 0, 0);
            }
        }
        unsigned short* CbY = Cb + (size_t)rr * nh;
#pragma unroll
        for (int mt = 0; mt < 2; ++mt)
#pragma unroll
            for (int reg = 0; reg < 4; ++reg) {
                int row = rowBase + wave * 32 + mt * 16 + rquad + reg;
                if (row >= M) continue;
#pragma unroll
                for (int nt = 0; nt < 8; ++nt)
                    CbY[(size_t)row * Hd + nt * 16 + lm] = f2bf(acc[mt][nt][reg]);
            }
    }
}

// ---------- gather: one wave per dst node, register accumulate, no atomics ----------
__global__ __launch_bounds__(256) void gather_kernel(const unsigned short* __restrict__ xr,
                                                     const int* __restrict__ row_ptr,
                                                     const unsigned int* __restrict__ epk,
                                                     const float* __restrict__ inv,
                                                     float* __restrict__ acc,
                                                     int N, int r0, int r1) {
    const int lane = threadIdx.x & 63;
    const int node = (blockIdx.x * 256 + threadIdx.x) >> 6;
    if (node >= N) return;
    const int beg = row_ptr[node], end = row_ptr[node + 1];
    float winv = 0.f;
    if (lane < (r1 - r0)) winv = inv[(size_t)(r0 + lane) * N + node];
    const unsigned int* xr32 = (const unsigned int*)xr;   // 2 bf16 per uint
    const size_t NH2 = (size_t)N * (Hd / 2);
    float a0 = 0.f, a1 = 0.f;
    for (int e = beg; e < end; ++e) {
        unsigned int p = epk[e];                 // wave-uniform
        int rel = (int)(p & 7u);
        if (rel < r0 || rel >= r1) continue;
        int srcn = (int)(p >> 3);
        float w = __shfl(winv, rel - r0);
        unsigned int val = xr32[(size_t)(rel - r0) * NH2 + srcn * (Hd / 2) + lane];
        a0 = fmaf(__uint_as_float(val << 16), w, a0);
        a1 = fmaf(__uint_as_float(val & 0xffff0000u), w, a1);
    }
    float* ap = &acc[(size_t)node * Hd + 2 * lane];
    ap[0] += a0;
    ap[1] += a1;
}

// ---------- classifier: out[i] = relu(acc[i]) . Wc + bc ----------
__global__ __launch_bounds__(256) void classify_kernel(const float* __restrict__ acc,
                                                       const float* __restrict__ Wc,
                                                       const float* __restrict__ bc,
                                                       float* __restrict__ out, int N) {
    int wave = (blockIdx.x * 256 + threadIdx.x) >> 6;
    int lane = threadIdx.x & 63;
    if (wave >= N) return;
    float s = fmaxf(acc[(size_t)wave * Hd + lane], 0.f) * Wc[lane]
            + fmaxf(acc[(size_t)wave * Hd + 64 + lane], 0.f) * Wc[64 + lane];
#pragma unroll
    for (int off = 32; off > 0; off >>= 1) s += __shfl_down(s, off);
    if (lane == 0) out[wave] = s + bc[0];
}

extern "C" void kernel_launch(void* const* d_in, const int* in_sizes, int n_in,
                              void* d_out, int out_size, void* d_ws, size_t ws_size,
                              hipStream_t stream) {
    const float* x     = (const float*)d_in[0];
    const int*   ei    = (const int*)d_in[1];
    const int*   et    = (const int*)d_in[2];
    const float* W1    = (const float*)d_in[3];
    const float* root1 = (const float*)d_in[4];
    const float* b1    = (const float*)d_in[5];
    const float* W2    = (const float*)d_in[6];
    const float* root2 = (const float*)d_in[7];
    const float* b2    = (const float*)d_in[8];
    const float* Wc    = (const float*)d_in[9];
    const float* bc    = (const float*)d_in[10];
    float* out = (float*)d_out;

    const int N = in_sizes[0] / Hd;
    const int E = in_sizes[2];
    const int R = in_sizes[3] / (Hd * Hd);
    const int* src  = ei;
    const int* dstp = ei + E;

    const size_t NH = (size_t)N * Hd;
    const size_t RN = (size_t)R * N;

    size_t off = 0;
    auto carve = [&](size_t bytes) -> char* {
        char* p = (char*)d_ws + off;
        off += (bytes + 255) & ~(size_t)255;
        return p;
    };
    float*          accb   = (float*)carve(NH * 4);
    unsigned short* xbf    = (unsigned short*)carve(NH * 2);
    unsigned short* Bt     = (unsigned short*)carve((size_t)2 * 9 * 16384 * 2);
    int*            cnt    = (int*)carve((RN + N) * 4);       // cnt[R*N] | cntd[N]
    int*            cntd   = cnt + RN;
    float*          inv    = (float*)carve(RN * 4);
    int*            rowp   = (int*)carve((size_t)(N + 1) * 4);
    int*            cursor = (int*)carve((size_t)N * 4);
    unsigned int*   epk    = (unsigned int*)carve((size_t)E * 4);
    int RC = R;
    while (RC > 1 && off + (size_t)RC * NH * 2 > ws_size) RC >>= 1;
    if (off + (size_t)RC * NH * 2 > ws_size) return;
    unsigned short* xr = (unsigned short*)((char*)d_ws + off);

    // graph prep (per call — no persistent state allowed)
    const int RNtot = (int)(RN + N);
    zero_kernel<<<(RNtot + 255) / 256, 256, 0, stream>>>(cnt, RNtot);
    count_kernel<<<(E + 255) / 256, 256, 0, stream>>>(dstp, et, cnt, cntd, E, N);
    inv_kernel<<<((int)RN + 255) / 256, 256, 0, stream>>>(cnt, inv, (int)RN);
    scan_kernel<<<1, 1024, 0, stream>>>(cntd, rowp, cursor, N, E);
    place_kernel<<<(E + 255) / 256, 256, 0, stream>>>(src, dstp, et, cursor, epk, E);

    const int n4 = (int)(NH / 4);
    cvt_bf16_kernel<<<(n4 + 255) / 256, 256, 0, stream>>>(x, xbf, n4, 0);

    prep_w_kernel<<<1, 256, 0, stream>>>(root1, Bt);
    prep_w_kernel<<<R, 256, 0, stream>>>(W1,    Bt + (size_t)1 * 16384);
    prep_w_kernel<<<1, 256, 0, stream>>>(root2, Bt + (size_t)9 * 16384);
    prep_w_kernel<<<R, 256, 0, stream>>>(W2,    Bt + (size_t)10 * 16384);

    const int Mtiles = (N + 127) / 128;
    const int gatherBlocks = (N + 3) / 4;

    for (int layer = 0; layer < 2; ++layer) {
        const unsigned short* BtL = Bt + (size_t)layer * 9 * 16384;
        const float* bias = layer ? b2 : b1;
        gemm_root<<<Mtiles, 256, 0, stream>>>(xbf, BtL, bias, accb, N);
        for (int r0 = 0; r0 < R; r0 += RC) {
            int rc = min(RC, R - r0);
            gemm_rel<<<Mtiles, 256, 0, stream>>>(xbf, BtL + (size_t)(1 + r0) * 16384,
                                                 xr, N, rc, (int)NH);
            gather_kernel<<<gatherBlocks, 256, 0, stream>>>(xr, rowp, epk, inv, accb,
                                                            N, r0, r0 + rc);
        }
        if (layer == 0)
            cvt_bf16_kernel<<<(n4 + 255) / 256, 256, 0, stream>>>(accb, xbf, n4, 1);
    }

    classify_kernel<<<(N + 3) / 4, 256, 0, stream>>>(accb, Wc, bc, out, N);
}

// Round 4
// 440.772 us; speedup vs baseline: 4.1677x; 1.1396x over previous
//
#include <hip/hip_runtime.h>

#define Hd 128
#define LDA 136   // LDS leading dim (bf16 elems)

typedef __attribute__((ext_vector_type(8))) short short8;   // 8 bf16 = 4 VGPRs
typedef __attribute__((ext_vector_type(4))) float f32x4;

__device__ __forceinline__ unsigned short f2bf(float f) {
    union { float f; unsigned u; } v; v.f = f;
    unsigned r = v.u + 0x7FFFu + ((v.u >> 16) & 1u);   // RNE
    return (unsigned short)(r >> 16);
}

// ---------- graph prep ----------
__global__ __launch_bounds__(256) void zero_kernel(int* __restrict__ p, int n) {
    int i = blockIdx.x * 256 + threadIdx.x;
    if (i < n) p[i] = 0;
}

__global__ __launch_bounds__(256) void count_kernel(const int* __restrict__ dst,
                                                    const int* __restrict__ et,
                                                    int* __restrict__ cnt,
                                                    int* __restrict__ cntd, int E, int N) {
    int e = blockIdx.x * 256 + threadIdx.x;
    if (e < E) {
        int d = dst[e];
        atomicAdd(&cnt[et[e] * N + d], 1);
        atomicAdd(&cntd[d], 1);
    }
}

__global__ __launch_bounds__(256) void inv_kernel(const int* __restrict__ cnt,
                                                  float* __restrict__ inv, int n) {
    int i = blockIdx.x * 256 + threadIdx.x;
    if (i < n) inv[i] = 1.0f / (float)max(cnt[i], 1);
}

// ---------- multi-block exclusive scan of cntd[N] ----------
__global__ __launch_bounds__(256) void reduce_kernel(const int* __restrict__ cntd,
                                                     int* __restrict__ bsum, int N) {
    __shared__ int ws[4];
    const int tid = threadIdx.x;
    int i = blockIdx.x * 256 + tid;
    int v = (i < N) ? cntd[i] : 0;
#pragma unroll
    for (int off = 32; off > 0; off >>= 1) v += __shfl_down(v, off);
    if ((tid & 63) == 0) ws[tid >> 6] = v;
    __syncthreads();
    if (tid == 0) bsum[blockIdx.x] = ws[0] + ws[1] + ws[2] + ws[3];
}

// single block: in-place exclusive scan of bsum[B] (chunked, B arbitrary)
__global__ __launch_bounds__(256) void scanb_kernel(int* __restrict__ bsum, int B) {
    __shared__ int wsum[4];
    __shared__ int carry_s;
    const int tid = threadIdx.x;
    const int lane = tid & 63, wid = tid >> 6;
    if (tid == 0) carry_s = 0;
    __syncthreads();
    for (int c = 0; c < B; c += 256) {
        int idx = c + tid;
        int x = (idx < B) ? bsum[idx] : 0;
        int incl = x;
#pragma unroll
        for (int off = 1; off < 64; off <<= 1) {
            int t = __shfl_up(incl, off);
            if (lane >= off) incl += t;
        }
        if (lane == 63) wsum[wid] = incl;
        __syncthreads();
        int wpre = 0;
        for (int k = 0; k < wid; ++k) wpre += wsum[k];
        int ex = incl - x + wpre + carry_s;
        if (idx < B) bsum[idx] = ex;
        __syncthreads();
        if (tid == 0) carry_s += wsum[0] + wsum[1] + wsum[2] + wsum[3];
        __syncthreads();
    }
}

__global__ __launch_bounds__(256) void apply_kernel(const int* __restrict__ cntd,
                                                    const int* __restrict__ bsum,
                                                    int* __restrict__ rowp,
                                                    int* __restrict__ cursor, int N, int E) {
    __shared__ int wsum[4];
    const int tid = threadIdx.x;
    const int lane = tid & 63, wid = tid >> 6;
    int i = blockIdx.x * 256 + tid;
    int x = (i < N) ? cntd[i] : 0;
    int incl = x;
#pragma unroll
    for (int off = 1; off < 64; off <<= 1) {
        int t = __shfl_up(incl, off);
        if (lane >= off) incl += t;
    }
    if (lane == 63) wsum[wid] = incl;
    __syncthreads();
    int wpre = 0;
    for (int k = 0; k < wid; ++k) wpre += wsum[k];
    int ex = incl - x + wpre + bsum[blockIdx.x];
    if (i < N) { rowp[i] = ex; cursor[i] = ex; }
    if (i == 0) rowp[N] = E;
}

// counting-sort placement: epk sorted by dst, payload = (src<<3)|rel
__global__ __launch_bounds__(256) void place_kernel(const int* __restrict__ src,
                                                    const int* __restrict__ dst,
                                                    const int* __restrict__ et,
                                                    int* __restrict__ cursor,
                                                    unsigned int* __restrict__ epk, int E) {
    int e = blockIdx.x * 256 + threadIdx.x;
    if (e < E) {
        int pos = atomicAdd(&cursor[dst[e]], 1);
        epk[pos] = ((unsigned int)src[e] << 3) | (unsigned int)et[e];
    }
}

// ---------- dtype prep ----------
__global__ __launch_bounds__(256) void cvt_bf16_kernel(const float* __restrict__ in,
                                                       unsigned short* __restrict__ out,
                                                       int n4) {
    int i = blockIdx.x * 256 + threadIdx.x;
    if (i >= n4) return;
    float4 v = ((const float4*)in)[i];
    ushort4 o;
    o.x = f2bf(v.x); o.y = f2bf(v.y); o.z = f2bf(v.z); o.w = f2bf(v.w);
    ((ushort4*)out)[i] = o;
}

// One 128x128 matrix per block: Bt[n*128+k] = bf16(W[k*128+n])
__global__ __launch_bounds__(256) void prep_w_kernel(const float* __restrict__ W,
                                                     unsigned short* __restrict__ Bt) {
    __shared__ float S[128 * 129];
    const float* Ws = W + (size_t)blockIdx.x * 16384;
    unsigned short* Bd = Bt + (size_t)blockIdx.x * 16384;
    const int tid = threadIdx.x;
#pragma unroll 8
    for (int i = 0; i < 64; ++i) {
        int idx = i * 256 + tid;
        S[(idx >> 7) * 129 + (idx & 127)] = Ws[idx];
    }
    __syncthreads();
#pragma unroll 8
    for (int i = 0; i < 64; ++i) {
        int idx = i * 256 + tid;
        int n = idx >> 7, k = idx & 127;
        Bd[idx] = f2bf(S[k * 129 + n]);
    }
}

// ---------- input-space aggregation: agg[r,i] = inv[r,i] * sum_{(j->i) rel r} x[j] ----------
// one wave per dst node; 8 relation accumulators in registers (rel is wave-uniform per edge)
__global__ __launch_bounds__(256) void gather_agg(const unsigned short* __restrict__ xsrc,
                                                  const int* __restrict__ row_ptr,
                                                  const unsigned int* __restrict__ epk,
                                                  const float* __restrict__ inv,
                                                  unsigned short* __restrict__ agg, int N) {
    const int lane = threadIdx.x & 63;
    const int node = (blockIdx.x * 256 + threadIdx.x) >> 6;
    if (node >= N) return;
    const int beg = row_ptr[node], end = row_ptr[node + 1];
    float winv = (lane < 8) ? inv[(size_t)lane * N + node] : 0.f;
    const unsigned int* x32 = (const unsigned int*)xsrc;   // 2 bf16 per uint

    float a[8][2];
#pragma unroll
    for (int r = 0; r < 8; ++r) { a[r][0] = 0.f; a[r][1] = 0.f; }

#define ACC_ADD(P, V)                                                        \
    {                                                                        \
        float f0 = __uint_as_float((V) << 16);                               \
        float f1 = __uint_as_float((V) & 0xffff0000u);                       \
        switch ((P) & 7u) {                                                  \
            case 0: a[0][0] += f0; a[0][1] += f1; break;                     \
            case 1: a[1][0] += f0; a[1][1] += f1; break;                     \
            case 2: a[2][0] += f0; a[2][1] += f1; break;                     \
            case 3: a[3][0] += f0; a[3][1] += f1; break;                     \
            case 4: a[4][0] += f0; a[4][1] += f1; break;                     \
            case 5: a[5][0] += f0; a[5][1] += f1; break;                     \
            case 6: a[6][0] += f0; a[6][1] += f1; break;                     \
            default: a[7][0] += f0; a[7][1] += f1; break;                    \
        }                                                                    \
    }

    int e = beg;
    for (; e + 1 < end; e += 2) {       // 2-way unroll for memory-level parallelism
        unsigned int p0 = epk[e], p1 = epk[e + 1];
        unsigned int v0 = x32[(size_t)(p0 >> 3) * 64 + lane];
        unsigned int v1 = x32[(size_t)(p1 >> 3) * 64 + lane];
        ACC_ADD(p0, v0);
        ACC_ADD(p1, v1);
    }
    if (e < end) {
        unsigned int p0 = epk[e];
        unsigned int v0 = x32[(size_t)(p0 >> 3) * 64 + lane];
        ACC_ADD(p0, v0);
    }
#undef ACC_ADD

    const size_t NH2 = (size_t)N * 64;
    unsigned int* agg32 = (unsigned int*)agg;
#pragma unroll
    for (int r = 0; r < 8; ++r) {
        float w = __shfl(winv, r);
        unsigned int lo = f2bf(a[r][0] * w);
        unsigned int hi = f2bf(a[r][1] * w);
        agg32[(size_t)r * NH2 + (size_t)node * 64 + lane] = lo | (hi << 16);
    }
}

// ---------- fused layer GEMM: acc = A0@Bt[0] + sum_r agg[r]@Bt[1+r]  (K_eff = 1152) ----------
// mode 1: outb[row,col] = bf16(relu(acc + bias[col]))          (layer 1 -> next features)
// mode 2: outf[row]     = relu(acc + bias) . Wc + bc           (layer 2 + classifier fused)
__global__ __launch_bounds__(256, 2) void gemm_fused(const unsigned short* __restrict__ A0,
                                                     const unsigned short* __restrict__ agg,
                                                     const unsigned short* __restrict__ Bt9,
                                                     const float* __restrict__ bias,
                                                     const float* __restrict__ Wc,
                                                     const float* __restrict__ bc,
                                                     unsigned short* __restrict__ outb,
                                                     float* __restrict__ outf,
                                                     int M, int mode) {
    __shared__ __align__(16) unsigned short As[128 * LDA];
    __shared__ __align__(16) unsigned short Bs[128 * LDA];
    const int tid = threadIdx.x;
    const int rowBase = blockIdx.x * 128;
    const int wave = tid >> 6, lane = tid & 63;
    const int lm = lane & 15, lk = (lane >> 4) * 8;
    const size_t NH = (size_t)M * Hd;

    f32x4 acc[2][8];
#pragma unroll
    for (int mt = 0; mt < 2; ++mt)
#pragma unroll
        for (int nt = 0; nt < 8; ++nt) acc[mt][nt] = (f32x4){0.f, 0.f, 0.f, 0.f};

    for (int t = 0; t < 9; ++t) {
        const unsigned short* At = (t == 0) ? A0 : agg + (size_t)(t - 1) * NH;
        const unsigned short* Btt = Bt9 + (size_t)t * 16384;
        __syncthreads();   // previous tile's LDS reads complete
#pragma unroll
        for (int i = 0; i < 8; ++i) {
            int idx = i * 256 + tid;
            int r = idx >> 4, c16 = idx & 15;
            int grow = rowBase + r; if (grow >= M) grow = M - 1;
            *(float4*)&As[r * LDA + c16 * 8] = *(const float4*)&At[(size_t)grow * Hd + c16 * 8];
            *(float4*)&Bs[r * LDA + c16 * 8] = *(const float4*)&Btt[idx * 8];
        }
        __syncthreads();
#pragma unroll
        for (int ks = 0; ks < 4; ++ks) {
            const int k0 = ks * 32 + lk;
            short8 af0 = *(const short8*)&As[(wave * 32 + lm) * LDA + k0];
            short8 af1 = *(const short8*)&As[(wave * 32 + 16 + lm) * LDA + k0];
#pragma unroll
            for (int nt = 0; nt < 8; ++nt) {
                short8 bf = *(const short8*)&Bs[(nt * 16 + lm) * LDA + k0];
                acc[0][nt] = __builtin_amdgcn_mfma_f32_16x16x32_bf16(af0, bf, acc[0][nt], 0, 0, 0);
                acc[1][nt] = __builtin_amdgcn_mfma_f32_16x16x32_bf16(af1, bf, acc[1][nt], 0, 0, 0);
            }
        }
    }

    // epilogue. C/D layout: col = nt*16 + lm, row = wave*32 + mt*16 + (lane>>4)*4 + reg
    const int rquad = (lane >> 4) * 4;
    float biasr[8], wc[8];
#pragma unroll
    for (int nt = 0; nt < 8; ++nt) biasr[nt] = bias[nt * 16 + lm];
    if (mode == 2) {
#pragma unroll
        for (int nt = 0; nt < 8; ++nt) wc[nt] = Wc[nt * 16 + lm];
    }
    const float bc0 = (mode == 2) ? bc[0] : 0.f;

#pragma unroll
    for (int mt = 0; mt < 2; ++mt)
#pragma unroll
        for (int reg = 0; reg < 4; ++reg) {
            int row = rowBase + wave * 32 + mt * 16 + rquad + reg;
            if (mode == 1) {
                if (row >= M) continue;
#pragma unroll
                for (int nt = 0; nt < 8; ++nt) {
                    float v = fmaxf(acc[mt][nt][reg] + biasr[nt], 0.f);
                    outb[(size_t)row * Hd + nt * 16 + lm] = f2bf(v);
                }
            } else {
                float s = 0.f;
#pragma unroll
                for (int nt = 0; nt < 8; ++nt)
                    s += fmaxf(acc[mt][nt][reg] + biasr[nt], 0.f) * wc[nt];
                s += __shfl_xor(s, 1);
                s += __shfl_xor(s, 2);
                s += __shfl_xor(s, 4);
                s += __shfl_xor(s, 8);
                if (lm == 0 && row < M) outf[row] = s + bc0;
            }
        }
}

extern "C" void kernel_launch(void* const* d_in, const int* in_sizes, int n_in,
                              void* d_out, int out_size, void* d_ws, size_t ws_size,
                              hipStream_t stream) {
    const float* x     = (const float*)d_in[0];
    const int*   ei    = (const int*)d_in[1];
    const int*   et    = (const int*)d_in[2];
    const float* W1    = (const float*)d_in[3];
    const float* root1 = (const float*)d_in[4];
    const float* b1    = (const float*)d_in[5];
    const float* W2    = (const float*)d_in[6];
    const float* root2 = (const float*)d_in[7];
    const float* b2    = (const float*)d_in[8];
    const float* Wc    = (const float*)d_in[9];
    const float* bc    = (const float*)d_in[10];
    float* out = (float*)d_out;

    const int N = in_sizes[0] / Hd;
    const int E = in_sizes[2];
    const int R = in_sizes[3] / (Hd * Hd);   // == 8
    const int* src  = ei;
    const int* dstp = ei + E;

    const size_t NH = (size_t)N * Hd;
    const size_t RN = (size_t)R * N;
    const int nBlocks = (N + 255) / 256;     // scan blocks

    size_t off = 0;
    auto carve = [&](size_t bytes) -> char* {
        char* p = (char*)d_ws + off;
        off += (bytes + 255) & ~(size_t)255;
        return p;
    };
    unsigned short* xbf    = (unsigned short*)carve(NH * 2);
    unsigned short* hbf    = (unsigned short*)carve(NH * 2);
    unsigned short* agg    = (unsigned short*)carve((size_t)R * NH * 2);
    unsigned short* Bt     = (unsigned short*)carve((size_t)2 * 9 * 16384 * 2);
    int*            cnt    = (int*)carve((RN + N) * 4);      // cnt[R*N] | cntd[N]
    int*            cntd   = cnt + RN;
    float*          inv    = (float*)carve(RN * 4);
    int*            rowp   = (int*)carve((size_t)(N + 1) * 4);
    int*            cursor = (int*)carve((size_t)N * 4);
    int*            bsum   = (int*)carve((size_t)nBlocks * 4);
    unsigned int*   epk    = (unsigned int*)carve((size_t)E * 4);
    if (off > ws_size) return;

    // graph prep
    const int RNtot = (int)(RN + N);
    zero_kernel<<<(RNtot + 255) / 256, 256, 0, stream>>>(cnt, RNtot);
    count_kernel<<<(E + 255) / 256, 256, 0, stream>>>(dstp, et, cnt, cntd, E, N);
    inv_kernel<<<((int)RN + 255) / 256, 256, 0, stream>>>(cnt, inv, (int)RN);
    reduce_kernel<<<nBlocks, 256, 0, stream>>>(cntd, bsum, N);
    scanb_kernel<<<1, 256, 0, stream>>>(bsum, nBlocks);
    apply_kernel<<<nBlocks, 256, 0, stream>>>(cntd, bsum, rowp, cursor, N, E);
    place_kernel<<<(E + 255) / 256, 256, 0, stream>>>(src, dstp, et, cursor, epk, E);

    // dtype prep
    const int n4 = (int)(NH / 4);
    cvt_bf16_kernel<<<(n4 + 255) / 256, 256, 0, stream>>>(x, xbf, n4);
    prep_w_kernel<<<1, 256, 0, stream>>>(root1, Bt);
    prep_w_kernel<<<R, 256, 0, stream>>>(W1,    Bt + (size_t)1 * 16384);
    prep_w_kernel<<<1, 256, 0, stream>>>(root2, Bt + (size_t)9 * 16384);
    prep_w_kernel<<<R, 256, 0, stream>>>(W2,    Bt + (size_t)10 * 16384);

    const int Mtiles = (N + 127) / 128;
    const int nodeBlocks = (N + 3) / 4;

    // layer 1: aggregate x -> agg; fused GEMM -> hbf (relu, bf16)
    gather_agg<<<nodeBlocks, 256, 0, stream>>>(xbf, rowp, epk, inv, agg, N);
    gemm_fused<<<Mtiles, 256, 0, stream>>>(xbf, agg, Bt, b1, nullptr, nullptr,
                                           hbf, nullptr, N, 1);
    // layer 2: aggregate hbf -> agg; fused GEMM + classifier -> out
    gather_agg<<<nodeBlocks, 256, 0, stream>>>(hbf, rowp, epk, inv, agg, N);
    gemm_fused<<<Mtiles, 256, 0, stream>>>(hbf, agg, Bt + (size_t)9 * 16384, b2, Wc, bc,
                                           nullptr, out, N, 2);
}

// Round 5
// 311.628 us; speedup vs baseline: 5.8949x; 1.4144x over previous
//
#include <hip/hip_runtime.h>

#define Hd 128
#define LDA 136   // LDS leading dim (bf16 elems)

typedef __attribute__((ext_vector_type(8))) short short8;   // 8 bf16 = 4 VGPRs
typedef __attribute__((ext_vector_type(4))) float f32x4;

__device__ __forceinline__ unsigned short f2bf(float f) {
    union { float f; unsigned u; } v; v.f = f;
    unsigned r = v.u + 0x7FFFu + ((v.u >> 16) & 1u);   // RNE
    return (unsigned short)(r >> 16);
}

// ---------- graph prep ----------
__global__ __launch_bounds__(256) void zero_kernel(int* __restrict__ p, int n) {
    int i = blockIdx.x * 256 + threadIdx.x;
    if (i < n) p[i] = 0;
}

// histogram over (dst*8 + rel) buckets
__global__ __launch_bounds__(256) void count_kernel(const int* __restrict__ dst,
                                                    const int* __restrict__ et,
                                                    int* __restrict__ cnt2, int E) {
    int e = blockIdx.x * 256 + threadIdx.x;
    if (e < E) atomicAdd(&cnt2[dst[e] * 8 + et[e]], 1);
}

__global__ __launch_bounds__(256) void inv_kernel(const int* __restrict__ cnt2,
                                                  float* __restrict__ inv2, int n) {
    int i = blockIdx.x * 256 + threadIdx.x;
    if (i < n) inv2[i] = 1.0f / (float)max(cnt2[i], 1);
}

// ---------- multi-block exclusive scan of cnt2[n2] -> cur (start offsets) ----------
__global__ __launch_bounds__(256) void reduce_kernel(const int* __restrict__ cnt2,
                                                     int* __restrict__ bsum, int n) {
    __shared__ int ws[4];
    const int tid = threadIdx.x;
    int i = blockIdx.x * 256 + tid;
    int v = (i < n) ? cnt2[i] : 0;
#pragma unroll
    for (int off = 32; off > 0; off >>= 1) v += __shfl_down(v, off);
    if ((tid & 63) == 0) ws[tid >> 6] = v;
    __syncthreads();
    if (tid == 0) bsum[blockIdx.x] = ws[0] + ws[1] + ws[2] + ws[3];
}

__global__ __launch_bounds__(256) void scanb_kernel(int* __restrict__ bsum, int B) {
    __shared__ int wsum[4];
    __shared__ int carry_s;
    const int tid = threadIdx.x;
    const int lane = tid & 63, wid = tid >> 6;
    if (tid == 0) carry_s = 0;
    __syncthreads();
    for (int c = 0; c < B; c += 256) {
        int idx = c + tid;
        int x = (idx < B) ? bsum[idx] : 0;
        int incl = x;
#pragma unroll
        for (int off = 1; off < 64; off <<= 1) {
            int t = __shfl_up(incl, off);
            if (lane >= off) incl += t;
        }
        if (lane == 63) wsum[wid] = incl;
        __syncthreads();
        int wpre = 0;
        for (int k = 0; k < wid; ++k) wpre += wsum[k];
        int ex = incl - x + wpre + carry_s;
        if (idx < B) bsum[idx] = ex;
        __syncthreads();
        if (tid == 0) carry_s += wsum[0] + wsum[1] + wsum[2] + wsum[3];
        __syncthreads();
    }
}

__global__ __launch_bounds__(256) void apply_kernel(const int* __restrict__ cnt2,
                                                    const int* __restrict__ bsum,
                                                    int* __restrict__ cur, int n) {
    __shared__ int wsum[4];
    const int tid = threadIdx.x;
    const int lane = tid & 63, wid = tid >> 6;
    int i = blockIdx.x * 256 + tid;
    int x = (i < n) ? cnt2[i] : 0;
    int incl = x;
#pragma unroll
    for (int off = 1; off < 64; off <<= 1) {
        int t = __shfl_up(incl, off);
        if (lane >= off) incl += t;
    }
    if (lane == 63) wsum[wid] = incl;
    __syncthreads();
    int wpre = 0;
    for (int k = 0; k < wid; ++k) wpre += wsum[k];
    if (i < n) cur[i] = incl - x + wpre + bsum[blockIdx.x];
}

// counting-sort placement: epk sorted by (dst,rel), payload = src.
// post-condition: cur[i] == end offset of bucket i (start of bucket i+1)
__global__ __launch_bounds__(256) void place_kernel(const int* __restrict__ src,
                                                    const int* __restrict__ dst,
                                                    const int* __restrict__ et,
                                                    int* __restrict__ cur,
                                                    unsigned int* __restrict__ epk, int E) {
    int e = blockIdx.x * 256 + threadIdx.x;
    if (e < E) {
        int pos = atomicAdd(&cur[dst[e] * 8 + et[e]], 1);
        epk[pos] = (unsigned int)src[e];
    }
}

// ---------- dtype prep ----------
__global__ __launch_bounds__(256) void cvt_bf16_kernel(const float* __restrict__ in,
                                                       unsigned short* __restrict__ out,
                                                       int n4) {
    int i = blockIdx.x * 256 + threadIdx.x;
    if (i >= n4) return;
    float4 v = ((const float4*)in)[i];
    ushort4 o;
    o.x = f2bf(v.x); o.y = f2bf(v.y); o.z = f2bf(v.z); o.w = f2bf(v.w);
    ((ushort4*)out)[i] = o;
}

// One 128x128 matrix per block: Bt[n*128+k] = bf16(W[k*128+n])
__global__ __launch_bounds__(256) void prep_w_kernel(const float* __restrict__ W,
                                                     unsigned short* __restrict__ Bt) {
    __shared__ float S[128 * 129];
    const float* Ws = W + (size_t)blockIdx.x * 16384;
    unsigned short* Bd = Bt + (size_t)blockIdx.x * 16384;
    const int tid = threadIdx.x;
#pragma unroll 8
    for (int i = 0; i < 64; ++i) {
        int idx = i * 256 + tid;
        S[(idx >> 7) * 129 + (idx & 127)] = Ws[idx];
    }
    __syncthreads();
#pragma unroll 8
    for (int i = 0; i < 64; ++i) {
        int idx = i * 256 + tid;
        int n = idx >> 7, k = idx & 127;
        Bd[idx] = f2bf(S[k * 129 + n]);
    }
}

// ---------- input-space aggregation over (dst,rel)-sorted CSR ----------
// one wave per dst node; 8 sequential relation segments, no relation dispatch logic.
// cur[i] holds bucket END offsets; start[i] = cur[i-1] (cur[-1] = 0).
__global__ __launch_bounds__(256) void gather_agg(const unsigned short* __restrict__ xsrc,
                                                  const int* __restrict__ cur,
                                                  const unsigned int* __restrict__ epk,
                                                  const float* __restrict__ inv2,
                                                  unsigned short* __restrict__ agg, int N) {
    const int lane = threadIdx.x & 63;
    const int node =
        __builtin_amdgcn_readfirstlane((int)((blockIdx.x * 256 + threadIdx.x) >> 6));
    if (node >= N) return;
    int b9 = 0;
    if (lane < 9) {
        int idx = node * 8 + lane - 1;
        b9 = (idx < 0) ? 0 : cur[idx];
    }
    float winv = (lane < 8) ? inv2[node * 8 + lane] : 0.f;
    const unsigned int* x32 = (const unsigned int*)xsrc;   // 2 bf16 per uint
    const size_t NH2 = (size_t)N * 64;
    unsigned int* agg32 = (unsigned int*)agg;

#pragma unroll
    for (int r = 0; r < 8; ++r) {
        const int beg = __builtin_amdgcn_readfirstlane(__shfl(b9, r));
        const int end = __builtin_amdgcn_readfirstlane(__shfl(b9, r + 1));
        float a0 = 0.f, a1 = 0.f;
        for (int e = beg; e < end; ++e) {
            unsigned int s = epk[e];                        // wave-uniform -> s_load
            unsigned int v = x32[(size_t)s * 64 + lane];
            a0 += __uint_as_float(v << 16);
            a1 += __uint_as_float(v & 0xffff0000u);
        }
        float w = __shfl(winv, r);
        unsigned int lo = f2bf(a0 * w);
        unsigned int hi = f2bf(a1 * w);
        agg32[(size_t)r * NH2 + (size_t)node * 64 + lane] = lo | (hi << 16);
    }
}

// ---------- fused layer GEMM: acc = A0@Bt[0] + sum_r agg[r]@Bt[1+r]  (K_eff = 1152) ----------
// mode 1: outb[row,col] = bf16(relu(acc + bias[col]))          (layer 1 -> next features)
// mode 2: outf[row]     = relu(acc + bias) . Wc + bc           (layer 2 + classifier fused)
__global__ __launch_bounds__(256, 2) void gemm_fused(const unsigned short* __restrict__ A0,
                                                     const unsigned short* __restrict__ agg,
                                                     const unsigned short* __restrict__ Bt9,
                                                     const float* __restrict__ bias,
                                                     const float* __restrict__ Wc,
                                                     const float* __restrict__ bc,
                                                     unsigned short* __restrict__ outb,
                                                     float* __restrict__ outf,
                                                     int M, int mode) {
    __shared__ __align__(16) unsigned short As[128 * LDA];
    __shared__ __align__(16) unsigned short Bs[128 * LDA];
    const int tid = threadIdx.x;
    const int rowBase = blockIdx.x * 128;
    const int wave = tid >> 6, lane = tid & 63;
    const int lm = lane & 15, lk = (lane >> 4) * 8;
    const size_t NH = (size_t)M * Hd;

    f32x4 acc[2][8];
#pragma unroll
    for (int mt = 0; mt < 2; ++mt)
#pragma unroll
        for (int nt = 0; nt < 8; ++nt) acc[mt][nt] = (f32x4){0.f, 0.f, 0.f, 0.f};

    for (int t = 0; t < 9; ++t) {
        const unsigned short* At = (t == 0) ? A0 : agg + (size_t)(t - 1) * NH;
        const unsigned short* Btt = Bt9 + (size_t)t * 16384;
        __syncthreads();   // previous tile's LDS reads complete
#pragma unroll
        for (int i = 0; i < 8; ++i) {
            int idx = i * 256 + tid;
            int r = idx >> 4, c16 = idx & 15;
            int grow = rowBase + r; if (grow >= M) grow = M - 1;
            *(float4*)&As[r * LDA + c16 * 8] = *(const float4*)&At[(size_t)grow * Hd + c16 * 8];
            *(float4*)&Bs[r * LDA + c16 * 8] = *(const float4*)&Btt[idx * 8];
        }
        __syncthreads();
#pragma unroll
        for (int ks = 0; ks < 4; ++ks) {
            const int k0 = ks * 32 + lk;
            short8 af0 = *(const short8*)&As[(wave * 32 + lm) * LDA + k0];
            short8 af1 = *(const short8*)&As[(wave * 32 + 16 + lm) * LDA + k0];
#pragma unroll
            for (int nt = 0; nt < 8; ++nt) {
                short8 bf = *(const short8*)&Bs[(nt * 16 + lm) * LDA + k0];
                acc[0][nt] = __builtin_amdgcn_mfma_f32_16x16x32_bf16(af0, bf, acc[0][nt], 0, 0, 0);
                acc[1][nt] = __builtin_amdgcn_mfma_f32_16x16x32_bf16(af1, bf, acc[1][nt], 0, 0, 0);
            }
        }
    }

    // epilogue. C/D layout: col = nt*16 + lm, row = wave*32 + mt*16 + (lane>>4)*4 + reg
    const int rquad = (lane >> 4) * 4;
    float biasr[8], wc[8];
#pragma unroll
    for (int nt = 0; nt < 8; ++nt) biasr[nt] = bias[nt * 16 + lm];
    if (mode == 2) {
#pragma unroll
        for (int nt = 0; nt < 8; ++nt) wc[nt] = Wc[nt * 16 + lm];
    }
    const float bc0 = (mode == 2) ? bc[0] : 0.f;

#pragma unroll
    for (int mt = 0; mt < 2; ++mt)
#pragma unroll
        for (int reg = 0; reg < 4; ++reg) {
            int row = rowBase + wave * 32 + mt * 16 + rquad + reg;
            if (mode == 1) {
                if (row >= M) continue;
#pragma unroll
                for (int nt = 0; nt < 8; ++nt) {
                    float v = fmaxf(acc[mt][nt][reg] + biasr[nt], 0.f);
                    outb[(size_t)row * Hd + nt * 16 + lm] = f2bf(v);
                }
            } else {
                float s = 0.f;
#pragma unroll
                for (int nt = 0; nt < 8; ++nt)
                    s += fmaxf(acc[mt][nt][reg] + biasr[nt], 0.f) * wc[nt];
                s += __shfl_xor(s, 1);
                s += __shfl_xor(s, 2);
                s += __shfl_xor(s, 4);
                s += __shfl_xor(s, 8);
                if (lm == 0 && row < M) outf[row] = s + bc0;
            }
        }
}

extern "C" void kernel_launch(void* const* d_in, const int* in_sizes, int n_in,
                              void* d_out, int out_size, void* d_ws, size_t ws_size,
                              hipStream_t stream) {
    const float* x     = (const float*)d_in[0];
    const int*   ei    = (const int*)d_in[1];
    const int*   et    = (const int*)d_in[2];
    const float* W1    = (const float*)d_in[3];
    const float* root1 = (const float*)d_in[4];
    const float* b1    = (const float*)d_in[5];
    const float* W2    = (const float*)d_in[6];
    const float* root2 = (const float*)d_in[7];
    const float* b2    = (const float*)d_in[8];
    const float* Wc    = (const float*)d_in[9];
    const float* bc    = (const float*)d_in[10];
    float* out = (float*)d_out;

    const int N = in_sizes[0] / Hd;
    const int E = in_sizes[2];
    const int R = in_sizes[3] / (Hd * Hd);   // == 8
    const int* src  = ei;
    const int* dstp = ei + E;

    const size_t NH = (size_t)N * Hd;
    const int n2 = N * 8;                    // (dst,rel) bucket count
    const int nBlocks2 = (n2 + 255) / 256;

    size_t off = 0;
    auto carve = [&](size_t bytes) -> char* {
        char* p = (char*)d_ws + off;
        off += (bytes + 255) & ~(size_t)255;
        return p;
    };
    unsigned short* xbf  = (unsigned short*)carve(NH * 2);
    unsigned short* hbf  = (unsigned short*)carve(NH * 2);
    unsigned short* agg  = (unsigned short*)carve((size_t)R * NH * 2);
    unsigned short* Bt   = (unsigned short*)carve((size_t)2 * 9 * 16384 * 2);
    int*            cnt2 = (int*)carve((size_t)n2 * 4);
    float*          inv2 = (float*)carve((size_t)n2 * 4);
    int*            cur  = (int*)carve((size_t)n2 * 4);
    int*            bsum = (int*)carve((size_t)nBlocks2 * 4);
    unsigned int*   epk  = (unsigned int*)carve((size_t)E * 4);
    if (off > ws_size) return;

    // graph prep: histogram -> inv + CSR over (dst*8+rel)
    zero_kernel<<<nBlocks2, 256, 0, stream>>>(cnt2, n2);
    count_kernel<<<(E + 255) / 256, 256, 0, stream>>>(dstp, et, cnt2, E);
    inv_kernel<<<nBlocks2, 256, 0, stream>>>(cnt2, inv2, n2);
    reduce_kernel<<<nBlocks2, 256, 0, stream>>>(cnt2, bsum, n2);
    scanb_kernel<<<1, 256, 0, stream>>>(bsum, nBlocks2);
    apply_kernel<<<nBlocks2, 256, 0, stream>>>(cnt2, bsum, cur, n2);
    place_kernel<<<(E + 255) / 256, 256, 0, stream>>>(src, dstp, et, cur, epk, E);

    // dtype prep
    const int n4 = (int)(NH / 4);
    cvt_bf16_kernel<<<(n4 + 255) / 256, 256, 0, stream>>>(x, xbf, n4);
    prep_w_kernel<<<1, 256, 0, stream>>>(root1, Bt);
    prep_w_kernel<<<R, 256, 0, stream>>>(W1,    Bt + (size_t)1 * 16384);
    prep_w_kernel<<<1, 256, 0, stream>>>(root2, Bt + (size_t)9 * 16384);
    prep_w_kernel<<<R, 256, 0, stream>>>(W2,    Bt + (size_t)10 * 16384);

    const int Mtiles = (N + 127) / 128;
    const int nodeBlocks = (N + 3) / 4;

    // layer 1: aggregate x -> agg; fused GEMM -> hbf (relu, bf16)
    gather_agg<<<nodeBlocks, 256, 0, stream>>>(xbf, cur, epk, inv2, agg, N);
    gemm_fused<<<Mtiles, 256, 0, stream>>>(xbf, agg, Bt, b1, nullptr, nullptr,
                                           hbf, nullptr, N, 1);
    // layer 2: aggregate hbf -> agg; fused GEMM + classifier -> out
    gather_agg<<<nodeBlocks, 256, 0, stream>>>(hbf, cur, epk, inv2, agg, N);
    gemm_fused<<<Mtiles, 256, 0, stream>>>(hbf, agg, Bt + (size_t)9 * 16384, b2, Wc, bc,
                                           nullptr, out, N, 2);
}